// Round 1
// baseline (1286.306 us; speedup 1.0000x reference)
//
#include <hip/hip_runtime.h>
#include <cstdint>

#define NB 4096   // batch
#define NL 1024   // L
#define NR 36     // R
#define NT 32     // T
#define NLK 256   // L/K

typedef __bf16 bf16x8 __attribute__((ext_vector_type(8)));
typedef float f32x4 __attribute__((ext_vector_type(4)));
typedef unsigned short u16;

typedef const __attribute__((address_space(1))) unsigned int* gas1_t;
typedef __attribute__((address_space(3))) unsigned int* las3_t;

__device__ __forceinline__ u16 f2bf(float x) {
  unsigned u = __builtin_bit_cast(unsigned, x);
  u += 0x7fffu + ((u >> 16) & 1u);   // RNE; inputs are well-behaved (no NaN)
  return (u16)(u >> 16);
}

__device__ __forceinline__ void gload_lds16(const void* g, void* l) {
  __builtin_amdgcn_global_load_lds((gas1_t)(uintptr_t)g, (las3_t)(uintptr_t)l, 16, 0, 0);
}

// ---------------- K1: s = sum_r img[b,r,:]; emit bf16(s), bf16(s^2) ----------------
__global__ __launch_bounds__(256) void k_sum_img(const float* __restrict__ img,
                                                 u16* __restrict__ Sbf,
                                                 u16* __restrict__ S2bf) {
  const int b = blockIdx.x;
  const int tid = threadIdx.x;
  const float4* base = (const float4*)(img + (size_t)b * NR * NL);
  float4 a = {0.f, 0.f, 0.f, 0.f};
#pragma unroll
  for (int r = 0; r < NR; ++r) {
    float4 v = base[r * (NL / 4) + tid];
    a.x += v.x; a.y += v.y; a.z += v.z; a.w += v.w;
  }
  ushort4 p1, p2;
  p1.x = f2bf(a.x); p1.y = f2bf(a.y); p1.z = f2bf(a.z); p1.w = f2bf(a.w);
  p2.x = f2bf(a.x * a.x); p2.y = f2bf(a.y * a.y); p2.z = f2bf(a.z * a.z); p2.w = f2bf(a.w * a.w);
  const size_t idx = (size_t)b * NL + tid * 4;
  *(ushort4*)(Sbf + idx) = p1;
  *(ushort4*)(S2bf + idx) = p2;
}

// ---------------- K2a: cap_repr = cap0 @ W_red^T + b_red;  inv_norm[b] ----------------
__global__ __launch_bounds__(256) void k_capred(const float* __restrict__ cap,
                                                const float* __restrict__ W_red,
                                                const float* __restrict__ b_red,
                                                float* __restrict__ cap_repr,
                                                float* __restrict__ inv_norm) {
  __shared__ float lc[16][NL];  // 64KB: 16 cap0 rows
  const int bs = blockIdx.x * 16;
  const int tid = threadIdx.x;
  // stage cap0 rows (row b lives at cap + b*T*L), one row per iteration, coalesced f4
#pragma unroll
  for (int i = 0; i < 16; ++i) {
    const float4* src = (const float4*)(cap + (size_t)(bs + i) * (NT * NL));
    ((float4*)lc[i])[tid] = src[tid];
  }
  __syncthreads();
  // norms: wave w handles rows w*4 .. w*4+3
  const int wv = tid >> 6, lane = tid & 63;
#pragma unroll
  for (int rr = 0; rr < 4; ++rr) {
    const int row = wv * 4 + rr;
    float s = 0.f;
#pragma unroll
    for (int j = 0; j < 16; ++j) {
      float v = lc[row][lane + 64 * j];
      s += v * v;
    }
    for (int off = 32; off > 0; off >>= 1) s += __shfl_down(s, off);
    if (lane == 0) inv_norm[bs + row] = 1.0f / sqrtf(s);
  }
  // GEMM1: thread = output channel o; 16 batch accumulators; W_red row streamed once
  const int o = tid;
  float acc[16];
#pragma unroll
  for (int bl = 0; bl < 16; ++bl) acc[bl] = 0.f;
  const float4* wrow = (const float4*)(W_red + (size_t)o * NL);
  for (int k4 = 0; k4 < NL / 4; ++k4) {
    float4 w = wrow[k4];
#pragma unroll
    for (int bl = 0; bl < 16; ++bl) {
      float4 c = *(const float4*)&lc[bl][k4 * 4];  // LDS broadcast
      acc[bl] += w.x * c.x + w.y * c.y + w.z * c.z + w.w * c.w;
    }
  }
  const float bias = b_red[o];
#pragma unroll
  for (int bl = 0; bl < 16; ++bl)
    cap_repr[(size_t)(bs + bl) * NLK + o] = acc[bl] + bias;
}

// ---------------- K2b: gate = sigmoid(cap_repr @ W_kp^T + b_kp); emit bf16(g*c_hat), bf16(g^2) ----------------
__global__ __launch_bounds__(256) void k_gate(const float* __restrict__ cap,
                                              const float* __restrict__ cap_repr,
                                              const float* __restrict__ W_kp,
                                              const float* __restrict__ b_kp,
                                              const float* __restrict__ inv_norm,
                                              u16* __restrict__ G1,
                                              u16* __restrict__ G2) {
  __shared__ float lcr[16 * NLK];  // 16KB
  const int bs = blockIdx.x * 16;
  const int tid = threadIdx.x;
  const float4* src = (const float4*)(cap_repr + (size_t)bs * NLK);
#pragma unroll
  for (int i = 0; i < 4; ++i) ((float4*)lcr)[tid + 256 * i] = src[tid + 256 * i];
  __syncthreads();
  float invn[16];
#pragma unroll
  for (int bl = 0; bl < 16; ++bl) invn[bl] = inv_norm[bs + bl];
  for (int jj = 0; jj < 4; ++jj) {
    const int j = tid + 256 * jj;
    float acc[16];
#pragma unroll
    for (int bl = 0; bl < 16; ++bl) acc[bl] = 0.f;
    const float4* wrow = (const float4*)(W_kp + (size_t)j * NLK);
    for (int k4 = 0; k4 < NLK / 4; ++k4) {
      float4 w = wrow[k4];
#pragma unroll
      for (int bl = 0; bl < 16; ++bl) {
        float4 c = *(const float4*)(lcr + bl * NLK + k4 * 4);  // LDS broadcast
        acc[bl] += w.x * c.x + w.y * c.y + w.z * c.z + w.w * c.w;
      }
    }
    const float bias = b_kp[j];
#pragma unroll
    for (int bl = 0; bl < 16; ++bl) {
      float z = acc[bl] + bias;
      float g = 1.f / (1.f + __expf(-z));
      float c0 = cap[(size_t)(bs + bl) * (NT * NL) + j];
      size_t oidx = (size_t)(bs + bl) * NL + j;
      G1[oidx] = f2bf(g * c0 * invn[bl]);
      G2[oidx] = f2bf(g * g);
    }
  }
}

// ---------------- K3: fused dual NT-GEMM + rsqrt epilogue ----------------
// out[i,j] = (S_i . G1_j) * rsqrt(S2_i . G2_j), M=N=4096, K=1024
__global__ __launch_bounds__(256, 2) void k_dualgemm(const u16* __restrict__ Sbf,
                                                     const u16* __restrict__ S2bf,
                                                     const u16* __restrict__ G1,
                                                     const u16* __restrict__ G2,
                                                     float* __restrict__ out) {
  __shared__ u16 sAll[4 * 128 * 32];  // A1 | A2 | B1 | B2, each 128x32 bf16 (8KB)
  const int tid = threadIdx.x;
  const int m0 = blockIdx.y * 128;
  const int n0 = blockIdx.x * 128;
  const u16* gbase[4] = {Sbf + (size_t)m0 * NL, S2bf + (size_t)m0 * NL,
                         G1 + (size_t)n0 * NL, G2 + (size_t)n0 * NL};
  const int lrow = tid >> 2;   // 0..63 (row within half-tile)
  const int lk8 = tid & 3;     // 16B chunk within 32-elem K row
  const int lane = tid & 63, wv = tid >> 6;
  const int wm = (wv >> 1) * 64, wn = (wv & 1) * 64;
  const int colsel = lane & 15, quad = lane >> 4;

  f32x4 acc1[4][4], acc2[4][4];
#pragma unroll
  for (int tm = 0; tm < 4; ++tm)
#pragma unroll
    for (int tn = 0; tn < 4; ++tn) {
      acc1[tm][tn] = (f32x4){0.f, 0.f, 0.f, 0.f};
      acc2[tm][tn] = (f32x4){0.f, 0.f, 0.f, 0.f};
    }

  const u16* sA1 = sAll;
  const u16* sA2 = sAll + 4096;
  const u16* sB1 = sAll + 8192;
  const u16* sB2 = sAll + 12288;

  for (int kt = 0; kt < NL / 32; ++kt) {
    const int k0 = kt * 32;
    __syncthreads();  // protect LDS from overwrite while prev compute in flight
#pragma unroll
    for (int j = 0; j < 8; ++j) {
      const int t = j >> 1, h = j & 1;
      const u16* g = gbase[t] + (size_t)((h * 64 + lrow) * NL + k0 + lk8 * 8);
      char* l = (char*)sAll + (size_t)(tid + 256 * j) * 16;  // lane-contiguous dest
      gload_lds16(g, l);
    }
    __syncthreads();  // drains vmcnt(0): staged tiles visible

    // --- numer: load frags then 16 MFMAs (live-range split vs denom to cap VGPR) ---
    {
      bf16x8 af[4], bf[4];
#pragma unroll
      for (int t = 0; t < 4; ++t) {
        af[t] = *(const bf16x8*)(sA1 + (wm + t * 16 + colsel) * 32 + quad * 8);
        bf[t] = *(const bf16x8*)(sB1 + (wn + t * 16 + colsel) * 32 + quad * 8);
      }
#pragma unroll
      for (int tm = 0; tm < 4; ++tm)
#pragma unroll
        for (int tn = 0; tn < 4; ++tn)
          acc1[tm][tn] = __builtin_amdgcn_mfma_f32_16x16x32_bf16(af[tm], bf[tn], acc1[tm][tn], 0, 0, 0);
    }
    // --- denom ---
    {
      bf16x8 af[4], bf[4];
#pragma unroll
      for (int t = 0; t < 4; ++t) {
        af[t] = *(const bf16x8*)(sA2 + (wm + t * 16 + colsel) * 32 + quad * 8);
        bf[t] = *(const bf16x8*)(sB2 + (wn + t * 16 + colsel) * 32 + quad * 8);
      }
#pragma unroll
      for (int tm = 0; tm < 4; ++tm)
#pragma unroll
        for (int tn = 0; tn < 4; ++tn)
          acc2[tm][tn] = __builtin_amdgcn_mfma_f32_16x16x32_bf16(af[tm], bf[tn], acc2[tm][tn], 0, 0, 0);
    }
  }

  // epilogue: C/D layout col=lane&15, row=quad*4+reg  [m89-verified]
#pragma unroll
  for (int tm = 0; tm < 4; ++tm)
#pragma unroll
    for (int tn = 0; tn < 4; ++tn)
#pragma unroll
      for (int r = 0; r < 4; ++r) {
        const int row = m0 + wm + tm * 16 + quad * 4 + r;
        const int col = n0 + wn + tn * 16 + colsel;
        out[(size_t)row * NB + col] = acc1[tm][tn][r] * rsqrtf(acc2[tm][tn][r]);
      }
}

extern "C" void kernel_launch(void* const* d_in, const int* in_sizes, int n_in,
                              void* d_out, int out_size, void* d_ws, size_t ws_size,
                              hipStream_t stream) {
  const float* img = (const float*)d_in[0];
  const float* cap = (const float*)d_in[1];
  // d_in[2] = lens: unused by reference
  const float* W_red = (const float*)d_in[3];
  const float* b_red = (const float*)d_in[4];
  const float* W_kp = (const float*)d_in[5];
  const float* b_kp = (const float*)d_in[6];
  float* out = (float*)d_out;

  char* ws = (char*)d_ws;
  u16* Sbf = (u16*)ws;                         // 8MB
  u16* S2bf = Sbf + (size_t)NB * NL;           // 8MB
  u16* G1 = S2bf + (size_t)NB * NL;            // 8MB
  u16* G2 = G1 + (size_t)NB * NL;              // 8MB
  float* cap_repr = (float*)(G2 + (size_t)NB * NL);  // 4MB
  float* inv_norm = cap_repr + (size_t)NB * NLK;     // 16KB   (total ~36MB)

  k_sum_img<<<NB, 256, 0, stream>>>(img, Sbf, S2bf);
  k_capred<<<NB / 16, 256, 0, stream>>>(cap, W_red, b_red, cap_repr, inv_norm);
  k_gate<<<NB / 16, 256, 0, stream>>>(cap, cap_repr, W_kp, b_kp, inv_norm, G1, G2);
  k_dualgemm<<<dim3(NB / 128, NB / 128), 256, 0, stream>>>(Sbf, S2bf, G1, G2, out);
}